// Round 15
// baseline (167.205 us; speedup 1.0000x reference)
//
#include <hip/hip_runtime.h>
#include <hip/hip_bf16.h>
#include <math.h>

#define Bq   8
#define DINq 256
#define Nq   2048

typedef __attribute__((ext_vector_type(8))) short bf16x8v;
typedef __attribute__((ext_vector_type(4))) float f32x4v;

__device__ __forceinline__ unsigned short f2bf(float f) {
  union { float f; unsigned u; } v; v.f = f;
  unsigned r = v.u + 0x7fffu + ((v.u >> 16) & 1u);
  return (unsigned short)(r >> 16);
}
__device__ __forceinline__ float bf2f(unsigned short h) {
  union { unsigned u; float f; } v; v.u = ((unsigned)h) << 16;
  return v.f;
}

__device__ __forceinline__ void gld_lds16(const void* g, void* l) {
  __builtin_amdgcn_global_load_lds(
      (const __attribute__((address_space(1))) unsigned int*)g,
      (__attribute__((address_space(3))) unsigned int*)l, 16, 0, 0);
}

// 8 mask bits -> 8 bf16 (1.0/0.0) packed as bf16x8v, element e = bit e.
__device__ __forceinline__ bf16x8v expand_mask(unsigned m8) {
  union { unsigned u[4]; bf16x8v v; } r;
  unsigned lo4 = ((m8 & 0xFu) * 0x204081u) & 0x01010101u;
  unsigned hi4 = (((m8 >> 4) & 0xFu) * 0x204081u) & 0x01010101u;
  r.u[0] = ((lo4 & 0xFFu) | ((lo4 & 0xFF00u) << 8)) * 0x3F80u;
  r.u[1] = (((lo4 >> 16) & 0xFFu) | ((lo4 >> 24) << 16)) * 0x3F80u;
  r.u[2] = ((hi4 & 0xFFu) | ((hi4 & 0xFF00u) << 8)) * 0x3F80u;
  r.u[3] = (((hi4 >> 16) & 0xFFu) | ((hi4 >> 24) << 16)) * 0x3F80u;
  return r.v;
}

// ---- w123[k] = (W^T a1)[k], (W^T a2)[k], (W^T a3)[k] ----
__global__ void k_prep(const float* __restrict__ W, const float* __restrict__ a,
                       float* __restrict__ w123) {
  __shared__ float red[3][4][256];
  const int k = threadIdx.x & 255, dq = threadIdx.x >> 8;
  float s1 = 0.f, s2 = 0.f, s3 = 0.f;
  for (int d = dq * 64; d < dq * 64 + 64; ++d) {
    float w = W[d * DINq + k];
    s1 += w * a[d];
    s2 += w * a[DINq + d];
    s3 += w * a[2 * DINq + d];
  }
  red[0][dq][k] = s1; red[1][dq][k] = s2; red[2][dq][k] = s3;
  __syncthreads();
  if (threadIdx.x < 256) {
    w123[k]            = red[0][0][k] + red[0][1][k] + red[0][2][k] + red[0][3][k];
    w123[DINq + k]     = red[1][0][k] + red[1][1][k] + red[1][2][k] + red[1][3][k];
    w123[2 * DINq + k] = red[2][0][k] + red[2][1][k] + red[2][2][k] + red[2][3][k];
  }
}

// ---- WT[k][d] = W[d][k] ----
__global__ void k_transposeW(const float* __restrict__ W, float* __restrict__ WT) {
  int d = blockIdx.x, k = threadIdx.x;
  WT[(size_t)k * DINq + d] = W[(size_t)d * DINq + k];
}

// ---- hX v4 (R13, direct-A/B winner): 4i x 8d register tile, full d=256/pass ----
__global__ __launch_bounds__(256, 2) void k_hX(const float* __restrict__ x,
                     const float* __restrict__ WT, const float* __restrict__ w123,
                     unsigned short* __restrict__ Xhi, unsigned short* __restrict__ Xlo,
                     float* __restrict__ tA, float* __restrict__ siA,
                     float* __restrict__ sbA) {
  __shared__ float xs[64][32];    // 8 KB   (k x i)
  __shared__ float ws[64][256];   // 64 KB  (k x d)
  __shared__ float wls[768];      // 3 KB
  __shared__ float Tt[32];
  const int tid = threadIdx.x;
  const int iq = tid & 7;         // 8 groups x 4 i = 32 i
  const int dg = tid >> 3;        // 32 groups x 8 d = 256 d
  const int i0 = blockIdx.x * 32;
  const int b = blockIdx.y;
  const int lane = tid & 63;
  const bool w0 = (tid < 64);
  const int ti = lane & 31;
  const int khalf = (lane >> 5) * 32;

  for (int n = tid; n < 768; n += 256) wls[n] = w123[n];

  float acc[4][8];
#pragma unroll
  for (int e = 0; e < 4; ++e)
#pragma unroll
    for (int cc = 0; cc < 8; ++cc) acc[e][cc] = 0.f;
  float p1 = 0.f, p2 = 0.f, p3 = 0.f;

  for (int kc = 0; kc < 4; ++kc) {
    __syncthreads();
#pragma unroll
    for (int l = 0; l < 2; ++l) {
      int c = l * 256 + tid;
      int r = c >> 3, ch = c & 7;
      gld_lds16(&x[((size_t)b * DINq + kc * 64 + r) * Nq + i0 + ch * 4], &xs[r][ch * 4]);
    }
#pragma unroll
    for (int l = 0; l < 16; ++l) {
      int c = l * 256 + tid;
      int r = c >> 6, ch = c & 63;
      gld_lds16(&WT[(size_t)(kc * 64 + r) * DINq + ch * 4], &ws[r][ch * 4]);
    }
    asm volatile("s_waitcnt vmcnt(0)" ::: "memory");
    __syncthreads();
#pragma unroll 4
    for (int kk = 0; kk < 64; ++kk) {
      f32x4v xv = *(const f32x4v*)&xs[kk][iq * 4];
      f32x4v wv0 = *(const f32x4v*)&ws[kk][dg * 8];
      f32x4v wv1 = *(const f32x4v*)&ws[kk][dg * 8 + 4];
#pragma unroll
      for (int e = 0; e < 4; ++e) {
#pragma unroll
        for (int cc = 0; cc < 4; ++cc) {
          acc[e][cc]     += xv[e] * wv0[cc];
          acc[e][cc + 4] += xv[e] * wv1[cc];
        }
      }
    }
    if (w0) {
#pragma unroll 4
      for (int k2 = 0; k2 < 32; ++k2) {
        int kk = khalf + k2;
        float xv = xs[kk][ti];
        p1 += xv * wls[kc * 64 + kk];
        p2 += xv * wls[256 + kc * 64 + kk];
        p3 += xv * wls[512 + kc * 64 + kk];
      }
    }
  }

  if (w0) {
    p1 += __shfl_xor(p1, 32, 64);
    p2 += __shfl_xor(p2, 32, 64);
    p3 += __shfl_xor(p3, 32, 64);
    if (lane < 32) {
      Tt[lane] = p3;
      tA[(size_t)b * Nq + i0 + lane] = p3;
      siA[(size_t)b * Nq + i0 + lane] = p1;
      sbA[(size_t)b * Nq + i0 + lane] = p2;
    }
  }
  __syncthreads();

  float tv[4];
#pragma unroll
  for (int e = 0; e < 4; ++e) tv[e] = Tt[iq * 4 + e];

#pragma unroll
  for (int cc = 0; cc < 8; ++cc) {
    const int d = dg * 8 + cc;
    unsigned short hv[4], lv[4];
#pragma unroll
    for (int e = 0; e < 4; ++e) {
      float Xv = tv[e] * acc[e][cc];
      unsigned short hs = f2bf(Xv);
      hv[e] = hs;
      lv[e] = f2bf(Xv - bf2f(hs));
    }
    size_t off = ((size_t)b * DINq + d) * Nq + i0 + iq * 4;
    *(ushort4*)&Xhi[off] = make_ushort4(hv[0], hv[1], hv[2], hv[3]);
    *(ushort4*)&Xlo[off] = make_ushort4(lv[0], lv[1], lv[2], lv[3]);
  }
}

// ---- bm[i][w] = bitmask of (adj[i][j]!=0), 32 j per word ----
__global__ void k_mask(const int* __restrict__ adj, unsigned* __restrict__ bm) {
  int wg = blockIdx.x * 256 + threadIdx.x;
  int i = wg >> 6, w = wg & 63, j0 = w * 32;
  const int4* ap = (const int4*)&adj[(size_t)i * Nq + j0];
  unsigned bits = 0;
#pragma unroll
  for (int q = 0; q < 8; ++q) {
    int4 a = ap[q];
    if (a.x) bits |= 1u << (q * 4);
    if (a.y) bits |= 1u << (q * 4 + 1);
    if (a.z) bits |= 1u << (q * 4 + 2);
    if (a.w) bits |= 1u << (q * 4 + 3);
  }
  bm[wg] = bits;
}

// ---- GEMM v6: R9 structure (256x128 tile, 64 MFMA/iter), but double-buffered
//      Bs (32KB) + 2 barriers/iter -> 50KB LDS -> 3 blocks/CU; coalesced sjp ----
__global__ __launch_bounds__(256, 3) void k_gemm(const unsigned* __restrict__ bm,
                                                 const unsigned short* __restrict__ Xhi,
                                                 const unsigned short* __restrict__ Xlo,
                                                 float* __restrict__ sjp) {
  __shared__ __align__(16) unsigned short Bs[2][2][128 * 32];  // 32 KB
  __shared__ unsigned bmlds[256 * 16];                         // 16 KB
  __shared__ float swb[4][128];                                // 2 KB
  const int tid = threadIdx.x;
  const int lane = tid & 63;
  const int wave = tid >> 6;
  const int wm = wave >> 1, wc = wave & 1;
  const int wg = blockIdx.x;
  const int xcd = wg & 7;
  const int sub = wg >> 3;            // [0,64)
  const int ct = xcd * 2 + (sub & 1);
  const int mt = (sub >> 1) & 7;
  const int ks = sub >> 4;            // [0,4)
  const int i0 = mt * 256, c0 = ct * 128, kbase = ks * 512;
  const int r15 = lane & 15, kg = lane >> 4;
  const int kb = 16 * (kg ^ ((r15 >> 1) & 3));

  // stage mask bits: 256 rows x 16 words (K=512), xor-swizzled by (row&15)
  {
    const int kw0 = kbase >> 5;
#pragma unroll
    for (int n = 0; n < 4; ++n) {
      int idx4 = n * 256 + tid;
      int r = idx4 >> 2, w4 = (idx4 & 3) * 4;
      uint4 v = *(const uint4*)&bm[(size_t)(i0 + r) * 64 + kw0 + w4];
      bmlds[r * 16 + ((w4 + 0) ^ (r & 15))] = v.x;
      bmlds[r * 16 + ((w4 + 1) ^ (r & 15))] = v.y;
      bmlds[r * 16 + ((w4 + 2) ^ (r & 15))] = v.z;
      bmlds[r * 16 + ((w4 + 3) ^ (r & 15))] = v.w;
    }
  }
  __syncthreads();

  f32x4v acc[8][4];
#pragma unroll
  for (int m = 0; m < 8; ++m)
#pragma unroll
    for (int n = 0; n < 4; ++n) acc[m][n] = (f32x4v)0.f;

  auto STAGE = [&](int buf, int t) {
    const int k0 = kbase + t * 32;
#pragma unroll
    for (int l = 0; l < 2; ++l) {
      const int pc = l * 256 + tid;
      const int row = pc >> 2, q = pc & 3;
      const int kc = 8 * (q ^ ((row >> 1) & 3));
      gld_lds16(&Xhi[(size_t)(c0 + row) * Nq + k0 + kc], &Bs[buf][0][pc * 8]);
      gld_lds16(&Xlo[(size_t)(c0 + row) * Nq + k0 + kc], &Bs[buf][1][pc * 8]);
    }
  };

  constexpr int NT = 16;  // 512 / 32
  STAGE(0, 0);
  int cb = 0;
  for (int t = 0; t < NT; ++t) {
    // Stage t+1 into buffer cb^1: its previous readers (tile t-1) all passed
    // the compute-done barrier of iter t-1, so the overwrite is race-free.
    if (t + 1 < NT) {
      STAGE(cb ^ 1, t + 1);
      asm volatile("s_waitcnt vmcnt(4)" ::: "memory");  // drain tile t, keep t+1 in flight
    } else {
      asm volatile("s_waitcnt vmcnt(0)" ::: "memory");
    }
    __builtin_amdgcn_sched_barrier(0);
    __builtin_amdgcn_s_barrier();       // stage-ready
    __builtin_amdgcn_sched_barrier(0);

    const char* Bh = (const char*)&Bs[cb][0][0];
    const char* Bl = (const char*)&Bs[cb][1][0];
    bf16x8v bfh[4], bfl[4];
#pragma unroll
    for (int n = 0; n < 4; ++n) {
      bfh[n] = *(const bf16x8v*)(Bh + (wc * 64 + n * 16 + r15) * 64 + kb);
      bfl[n] = *(const bf16x8v*)(Bl + (wc * 64 + n * 16 + r15) * 64 + kb);
    }
    const int jb = kbase + t * 32 + kg * 8;
#pragma unroll
    for (int m = 0; m < 8; ++m) {
      const int arow = wm * 128 + m * 16 + r15;
      unsigned wv = bmlds[arow * 16 + (t ^ (arow & 15))];
      unsigned m8 = (wv >> (kg * 8)) & 0xFFu;
      unsigned d = (unsigned)(i0 + arow - jb);
      if (d < 8u) m8 &= ~(1u << d);
      bf16x8v af = expand_mask(m8);
      __builtin_amdgcn_s_setprio(1);
#pragma unroll
      for (int n = 0; n < 4; ++n) {
        acc[m][n] = __builtin_amdgcn_mfma_f32_16x16x32_bf16(af, bfh[n], acc[m][n], 0, 0, 0);
        acc[m][n] = __builtin_amdgcn_mfma_f32_16x16x32_bf16(af, bfl[n], acc[m][n], 0, 0, 0);
      }
      __builtin_amdgcn_s_setprio(0);
    }
    if (t + 1 < NT) __builtin_amdgcn_s_barrier();  // compute-done: frees buf cb
    cb ^= 1;
  }

  // Fused epilogue: partial = sum_d acc * (Xhi+Xlo); division by t in k_sjsum.
  const int b = c0 >> 8;
  const int re = (lane >> 4) * 4, ce = lane & 15;
  float s[8][4];
#pragma unroll
  for (int m = 0; m < 8; ++m)
#pragma unroll
    for (int r = 0; r < 4; ++r) s[m][r] = 0.f;
#pragma unroll
  for (int n = 0; n < 4; ++n) {
    const size_t xrow = (size_t)(c0 + wc * 64 + n * 16 + ce) * Nq;
#pragma unroll
    for (int m = 0; m < 8; ++m) {
      const size_t ib = xrow + i0 + wm * 128 + m * 16 + re;
      ushort4 xh = *(const ushort4*)&Xhi[ib];
      ushort4 xl = *(const ushort4*)&Xlo[ib];
      s[m][0] += acc[m][n][0] * (bf2f(xh.x) + bf2f(xl.x));
      s[m][1] += acc[m][n][1] * (bf2f(xh.y) + bf2f(xl.y));
      s[m][2] += acc[m][n][2] * (bf2f(xh.z) + bf2f(xl.z));
      s[m][3] += acc[m][n][3] * (bf2f(xh.w) + bf2f(xl.w));
    }
  }
#pragma unroll
  for (int o = 1; o < 16; o <<= 1) {
#pragma unroll
    for (int m = 0; m < 8; ++m)
#pragma unroll
      for (int r = 0; r < 4; ++r) s[m][r] += __shfl_xor(s[m][r], o, 64);
  }
  // Coalesced sjp writes: repack per-wave 128 floats in LDS, store contiguously.
  if (ce == 0) {
#pragma unroll
    for (int m = 0; m < 8; ++m)
#pragma unroll
      for (int r = 0; r < 4; ++r)
        swb[wave][m * 16 + re + r] = s[m][r];
  }
  __builtin_amdgcn_s_barrier();
  {
    const int slice = (ct & 1) * 8 + ks * 2 + wc;
    float* sp = sjp + ((size_t)slice * Bq + b) * Nq + i0 + wm * 128;
    sp[lane] = swb[wave][lane];
    sp[64 + lane] = swb[wave][64 + lane];
  }
}

// ---- sjv[b,i] = sb[b,i] + (sum of 16 partial slices) / t[b,i] ----
__global__ void k_sjsum(const float* __restrict__ sbA, const float* __restrict__ tA,
                        const float* __restrict__ sjp, float* __restrict__ sjvA) {
  int idx = blockIdx.x * 256 + threadIdx.x;
  float s = 0.f;
#pragma unroll
  for (int sl = 0; sl < 16; ++sl) s += sjp[(size_t)sl * Bq * Nq + idx];
  sjvA[idx] = sbA[idx] + s / tA[idx];
}

// ---- out[b,i,:] = softmax_j( mask(bm, lrelu(si[b,i] + sjv[b,j])) ) ----
__global__ void k_softmax(const unsigned* __restrict__ bm, const float* __restrict__ siA,
                          const float* __restrict__ sjvA, float* __restrict__ out) {
  const int b = blockIdx.y, i = blockIdx.x, tid = threadIdx.x;
  const float siv = siA[(size_t)b * Nq + i];
  const unsigned* brow = bm + (size_t)i * 64;
  const float* sjb = sjvA + (size_t)b * Nq;
  const int bit = tid & 31;
  float sc[8];
  float mx = -3.0e38f;
#pragma unroll
  for (int s = 0; s < 8; ++s) {
    int j = s * 256 + tid;
    float v = siv + sjb[j];
    v = v > 0.f ? v : 0.2f * v;
    unsigned wv = brow[j >> 5];
    v = ((wv >> bit) & 1u) ? v : -9.0e15f;
    sc[s] = v;
    mx = fmaxf(mx, v);
  }
#pragma unroll
  for (int o = 32; o >= 1; o >>= 1) mx = fmaxf(mx, __shfl_xor(mx, o, 64));
  __shared__ float redm[4], reds[4];
  const int wave = tid >> 6, lane = tid & 63;
  if (lane == 0) redm[wave] = mx;
  __syncthreads();
  mx = fmaxf(fmaxf(redm[0], redm[1]), fmaxf(redm[2], redm[3]));
  float sum = 0.f, ex[8];
#pragma unroll
  for (int s = 0; s < 8; ++s) { ex[s] = expf(sc[s] - mx); sum += ex[s]; }
#pragma unroll
  for (int o = 32; o >= 1; o >>= 1) sum += __shfl_xor(sum, o, 64);
  if (lane == 0) reds[wave] = sum;
  __syncthreads();
  sum = reds[0] + reds[1] + reds[2] + reds[3];
  float inv = 1.f / sum;
  float* orow = out + ((size_t)b * Nq + i) * Nq;
#pragma unroll
  for (int s = 0; s < 8; ++s) orow[s * 256 + tid] = ex[s] * inv;
}

extern "C" void kernel_launch(void* const* d_in, const int* in_sizes, int n_in,
                              void* d_out, int out_size, void* d_ws, size_t ws_size,
                              hipStream_t stream) {
  const float* x = (const float*)d_in[0];
  const int* adj = (const int*)d_in[1];
  const float* W = (const float*)d_in[2];
  const float* a = (const float*)d_in[3];
  float* out = (float*)d_out;

  char* ws = (char*)d_ws;
  size_t off = 0;
  auto alloc = [&](size_t bytes) -> void* {
    void* p = ws + off;
    off += (bytes + 255) & ~(size_t)255;
    return p;
  };
  float* w123 = (float*)alloc(3 * DINq * sizeof(float));
  float* WT = (float*)alloc((size_t)DINq * DINq * sizeof(float));
  float* tA = (float*)alloc((size_t)Bq * Nq * sizeof(float));
  float* siA = (float*)alloc((size_t)Bq * Nq * sizeof(float));
  float* sbA = (float*)alloc((size_t)Bq * Nq * sizeof(float));
  float* sjvA = (float*)alloc((size_t)Bq * Nq * sizeof(float));
  float* sjp = (float*)alloc((size_t)16 * Bq * Nq * sizeof(float));
  unsigned short* Xhi = (unsigned short*)alloc((size_t)Nq * Nq * 2);
  unsigned short* Xlo = (unsigned short*)alloc((size_t)Nq * Nq * 2);
  unsigned* bm = (unsigned*)alloc((size_t)Nq * 64 * sizeof(unsigned));

  k_prep<<<dim3(1), dim3(1024), 0, stream>>>(W, a, w123);
  k_transposeW<<<dim3(DINq), dim3(DINq), 0, stream>>>(W, WT);
  k_hX<<<dim3(Nq / 32, Bq), dim3(256), 0, stream>>>(x, WT, w123, Xhi, Xlo, tA, siA, sbA);
  k_mask<<<dim3(Nq * 64 / 256), dim3(256), 0, stream>>>(adj, bm);
  k_gemm<<<dim3(512), dim3(256), 0, stream>>>(bm, Xhi, Xlo, sjp);
  k_sjsum<<<dim3(Bq * Nq / 256), dim3(256), 0, stream>>>(sbA, tA, sjp, sjvA);
  k_softmax<<<dim3(Nq, Bq), dim3(256), 0, stream>>>(bm, siA, sjvA, out);
}

// Round 16
// 129.648 us; speedup vs baseline: 1.2897x; 1.2897x over previous
//
#include <hip/hip_runtime.h>
#include <hip/hip_bf16.h>
#include <math.h>

#define Bq   8
#define DINq 256
#define Nq   2048

typedef __attribute__((ext_vector_type(8))) short bf16x8v;
typedef __attribute__((ext_vector_type(4))) float f32x4v;

__device__ __forceinline__ unsigned short f2bf(float f) {
  union { float f; unsigned u; } v; v.f = f;
  unsigned r = v.u + 0x7fffu + ((v.u >> 16) & 1u);
  return (unsigned short)(r >> 16);
}
__device__ __forceinline__ float bf2f(unsigned short h) {
  union { unsigned u; float f; } v; v.u = ((unsigned)h) << 16;
  return v.f;
}

__device__ __forceinline__ void gld_lds16(const void* g, void* l) {
  __builtin_amdgcn_global_load_lds(
      (const __attribute__((address_space(1))) unsigned int*)g,
      (__attribute__((address_space(3))) unsigned int*)l, 16, 0, 0);
}

// 8 mask bits -> 8 bf16 (1.0/0.0) packed as bf16x8v, element e = bit e.
__device__ __forceinline__ bf16x8v expand_mask(unsigned m8) {
  union { unsigned u[4]; bf16x8v v; } r;
  unsigned lo4 = ((m8 & 0xFu) * 0x204081u) & 0x01010101u;
  unsigned hi4 = (((m8 >> 4) & 0xFu) * 0x204081u) & 0x01010101u;
  r.u[0] = ((lo4 & 0xFFu) | ((lo4 & 0xFF00u) << 8)) * 0x3F80u;
  r.u[1] = (((lo4 >> 16) & 0xFFu) | ((lo4 >> 24) << 16)) * 0x3F80u;
  r.u[2] = ((hi4 & 0xFFu) | ((hi4 & 0xFF00u) << 8)) * 0x3F80u;
  r.u[3] = (((hi4 >> 16) & 0xFFu) | ((hi4 >> 24) << 16)) * 0x3F80u;
  return r.v;
}

// ---- w123[k] = (W^T a1)[k], (W^T a2)[k], (W^T a3)[k] ----
__global__ void k_prep(const float* __restrict__ W, const float* __restrict__ a,
                       float* __restrict__ w123) {
  __shared__ float red[3][4][256];
  const int k = threadIdx.x & 255, dq = threadIdx.x >> 8;
  float s1 = 0.f, s2 = 0.f, s3 = 0.f;
  for (int d = dq * 64; d < dq * 64 + 64; ++d) {
    float w = W[d * DINq + k];
    s1 += w * a[d];
    s2 += w * a[DINq + d];
    s3 += w * a[2 * DINq + d];
  }
  red[0][dq][k] = s1; red[1][dq][k] = s2; red[2][dq][k] = s3;
  __syncthreads();
  if (threadIdx.x < 256) {
    w123[k]            = red[0][0][k] + red[0][1][k] + red[0][2][k] + red[0][3][k];
    w123[DINq + k]     = red[1][0][k] + red[1][1][k] + red[1][2][k] + red[1][3][k];
    w123[2 * DINq + k] = red[2][0][k] + red[2][1][k] + red[2][2][k] + red[2][3][k];
  }
}

// ---- WT[k][d] = W[d][k] ----
__global__ void k_transposeW(const float* __restrict__ W, float* __restrict__ WT) {
  int d = blockIdx.x, k = threadIdx.x;
  WT[(size_t)k * DINq + d] = W[(size_t)d * DINq + k];
}

// ---- hX v4 (R13, bisect winner): 4i x 8d register tile, full d=256/pass ----
__global__ __launch_bounds__(256, 2) void k_hX(const float* __restrict__ x,
                     const float* __restrict__ WT, const float* __restrict__ w123,
                     unsigned short* __restrict__ Xhi, unsigned short* __restrict__ Xlo,
                     float* __restrict__ tA, float* __restrict__ siA,
                     float* __restrict__ sbA) {
  __shared__ float xs[64][32];    // 8 KB   (k x i)
  __shared__ float ws[64][256];   // 64 KB  (k x d)
  __shared__ float wls[768];      // 3 KB
  __shared__ float Tt[32];
  const int tid = threadIdx.x;
  const int iq = tid & 7;         // 8 groups x 4 i = 32 i
  const int dg = tid >> 3;        // 32 groups x 8 d = 256 d
  const int i0 = blockIdx.x * 32;
  const int b = blockIdx.y;
  const int lane = tid & 63;
  const bool w0 = (tid < 64);
  const int ti = lane & 31;
  const int khalf = (lane >> 5) * 32;

  for (int n = tid; n < 768; n += 256) wls[n] = w123[n];

  float acc[4][8];
#pragma unroll
  for (int e = 0; e < 4; ++e)
#pragma unroll
    for (int cc = 0; cc < 8; ++cc) acc[e][cc] = 0.f;
  float p1 = 0.f, p2 = 0.f, p3 = 0.f;

  for (int kc = 0; kc < 4; ++kc) {
    __syncthreads();
#pragma unroll
    for (int l = 0; l < 2; ++l) {
      int c = l * 256 + tid;
      int r = c >> 3, ch = c & 7;
      gld_lds16(&x[((size_t)b * DINq + kc * 64 + r) * Nq + i0 + ch * 4], &xs[r][ch * 4]);
    }
#pragma unroll
    for (int l = 0; l < 16; ++l) {
      int c = l * 256 + tid;
      int r = c >> 6, ch = c & 63;
      gld_lds16(&WT[(size_t)(kc * 64 + r) * DINq + ch * 4], &ws[r][ch * 4]);
    }
    asm volatile("s_waitcnt vmcnt(0)" ::: "memory");
    __syncthreads();
#pragma unroll 4
    for (int kk = 0; kk < 64; ++kk) {
      f32x4v xv = *(const f32x4v*)&xs[kk][iq * 4];
      f32x4v wv0 = *(const f32x4v*)&ws[kk][dg * 8];
      f32x4v wv1 = *(const f32x4v*)&ws[kk][dg * 8 + 4];
#pragma unroll
      for (int e = 0; e < 4; ++e) {
#pragma unroll
        for (int cc = 0; cc < 4; ++cc) {
          acc[e][cc]     += xv[e] * wv0[cc];
          acc[e][cc + 4] += xv[e] * wv1[cc];
        }
      }
    }
    if (w0) {
#pragma unroll 4
      for (int k2 = 0; k2 < 32; ++k2) {
        int kk = khalf + k2;
        float xv = xs[kk][ti];
        p1 += xv * wls[kc * 64 + kk];
        p2 += xv * wls[256 + kc * 64 + kk];
        p3 += xv * wls[512 + kc * 64 + kk];
      }
    }
  }

  if (w0) {
    p1 += __shfl_xor(p1, 32, 64);
    p2 += __shfl_xor(p2, 32, 64);
    p3 += __shfl_xor(p3, 32, 64);
    if (lane < 32) {
      Tt[lane] = p3;
      tA[(size_t)b * Nq + i0 + lane] = p3;
      siA[(size_t)b * Nq + i0 + lane] = p1;
      sbA[(size_t)b * Nq + i0 + lane] = p2;
    }
  }
  __syncthreads();

  float tv[4];
#pragma unroll
  for (int e = 0; e < 4; ++e) tv[e] = Tt[iq * 4 + e];

#pragma unroll
  for (int cc = 0; cc < 8; ++cc) {
    const int d = dg * 8 + cc;
    unsigned short hv[4], lv[4];
#pragma unroll
    for (int e = 0; e < 4; ++e) {
      float Xv = tv[e] * acc[e][cc];
      unsigned short hs = f2bf(Xv);
      hv[e] = hs;
      lv[e] = f2bf(Xv - bf2f(hs));
    }
    size_t off = ((size_t)b * DINq + d) * Nq + i0 + iq * 4;
    *(ushort4*)&Xhi[off] = make_ushort4(hv[0], hv[1], hv[2], hv[3]);
    *(ushort4*)&Xlo[off] = make_ushort4(lv[0], lv[1], lv[2], lv[3]);
  }
}

// ---- bm[i][w] = bitmask of (adj[i][j]!=0), 32 j per word ----
__global__ void k_mask(const int* __restrict__ adj, unsigned* __restrict__ bm) {
  int wg = blockIdx.x * 256 + threadIdx.x;
  int i = wg >> 6, w = wg & 63, j0 = w * 32;
  const int4* ap = (const int4*)&adj[(size_t)i * Nq + j0];
  unsigned bits = 0;
#pragma unroll
  for (int q = 0; q < 8; ++q) {
    int4 a = ap[q];
    if (a.x) bits |= 1u << (q * 4);
    if (a.y) bits |= 1u << (q * 4 + 1);
    if (a.z) bits |= 1u << (q * 4 + 2);
    if (a.w) bits |= 1u << (q * 4 + 3);
  }
  bm[wg] = bits;
}

// ---- GEMM (R9 structure, frozen): A = mask bits -> bf16 expansion, B = Xhi+Xlo
//      merged acc, tile 256x128, K-split x4, ct-grouped per XCD, tri-buffer
//      counted vmcnt. ONLY change vs R9: coalesced sjp epilogue stores. ----
__global__ __launch_bounds__(256, 2) void k_gemm(const unsigned* __restrict__ bm,
                                                 const unsigned short* __restrict__ Xhi,
                                                 const unsigned short* __restrict__ Xlo,
                                                 float* __restrict__ sjp) {
  __shared__ __align__(16) unsigned short Bs[3][2][128 * 32];  // 48 KB
  __shared__ unsigned bmlds[256 * 16];                         // 16 KB
  __shared__ float swb[4][128];                                // 2 KB
  const int tid = threadIdx.x;
  const int lane = tid & 63;
  const int wave = tid >> 6;
  const int wm = wave >> 1, wc = wave & 1;
  const int wg = blockIdx.x;
  const int xcd = wg & 7;
  const int sub = wg >> 3;            // [0,64)
  const int ct = xcd * 2 + (sub & 1);
  const int mt = (sub >> 1) & 7;
  const int ks = sub >> 4;            // [0,4)
  const int i0 = mt * 256, c0 = ct * 128, kbase = ks * 512;
  const int r15 = lane & 15, kg = lane >> 4;
  const int kb = 16 * (kg ^ ((r15 >> 1) & 3));

  {
    const int kw0 = kbase >> 5;
#pragma unroll
    for (int n = 0; n < 4; ++n) {
      int idx4 = n * 256 + tid;
      int r = idx4 >> 2, w4 = (idx4 & 3) * 4;
      uint4 v = *(const uint4*)&bm[(size_t)(i0 + r) * 64 + kw0 + w4];
      bmlds[r * 16 + ((w4 + 0) ^ (r & 15))] = v.x;
      bmlds[r * 16 + ((w4 + 1) ^ (r & 15))] = v.y;
      bmlds[r * 16 + ((w4 + 2) ^ (r & 15))] = v.z;
      bmlds[r * 16 + ((w4 + 3) ^ (r & 15))] = v.w;
    }
  }
  __syncthreads();

  f32x4v acc[8][4];
#pragma unroll
  for (int m = 0; m < 8; ++m)
#pragma unroll
    for (int n = 0; n < 4; ++n) acc[m][n] = (f32x4v)0.f;

  auto STAGE = [&](int buf, int t) {
    const int k0 = kbase + t * 32;
#pragma unroll
    for (int l = 0; l < 2; ++l) {
      const int pc = l * 256 + tid;
      const int row = pc >> 2, q = pc & 3;
      const int kc = 8 * (q ^ ((row >> 1) & 3));
      gld_lds16(&Xhi[(size_t)(c0 + row) * Nq + k0 + kc], &Bs[buf][0][pc * 8]);
      gld_lds16(&Xlo[(size_t)(c0 + row) * Nq + k0 + kc], &Bs[buf][1][pc * 8]);
    }
  };

  constexpr int NT = 16;  // 512 / 32
  STAGE(0, 0);
  STAGE(1, 1);
  int cb = 0, sb2 = 2;
  for (int t = 0; t < NT; ++t) {
    if (t + 1 < NT) {
      asm volatile("s_waitcnt vmcnt(4)" ::: "memory");
    } else {
      asm volatile("s_waitcnt vmcnt(0)" ::: "memory");
    }
    __builtin_amdgcn_sched_barrier(0);
    __builtin_amdgcn_s_barrier();
    __builtin_amdgcn_sched_barrier(0);
    if (t + 2 < NT) STAGE(sb2, t + 2);

    const char* Bh = (const char*)&Bs[cb][0][0];
    const char* Bl = (const char*)&Bs[cb][1][0];
    bf16x8v bfh[4], bfl[4];
#pragma unroll
    for (int n = 0; n < 4; ++n) {
      bfh[n] = *(const bf16x8v*)(Bh + (wc * 64 + n * 16 + r15) * 64 + kb);
      bfl[n] = *(const bf16x8v*)(Bl + (wc * 64 + n * 16 + r15) * 64 + kb);
    }
    const int jb = kbase + t * 32 + kg * 8;
#pragma unroll
    for (int m = 0; m < 8; ++m) {
      const int arow = wm * 128 + m * 16 + r15;
      unsigned wv = bmlds[arow * 16 + (t ^ (arow & 15))];
      unsigned m8 = (wv >> (kg * 8)) & 0xFFu;
      unsigned d = (unsigned)(i0 + arow - jb);
      if (d < 8u) m8 &= ~(1u << d);
      bf16x8v af = expand_mask(m8);
      __builtin_amdgcn_s_setprio(1);
#pragma unroll
      for (int n = 0; n < 4; ++n) {
        acc[m][n] = __builtin_amdgcn_mfma_f32_16x16x32_bf16(af, bfh[n], acc[m][n], 0, 0, 0);
        acc[m][n] = __builtin_amdgcn_mfma_f32_16x16x32_bf16(af, bfl[n], acc[m][n], 0, 0, 0);
      }
      __builtin_amdgcn_s_setprio(0);
    }
    cb = (cb == 2) ? 0 : cb + 1;
    sb2 = (sb2 == 2) ? 0 : sb2 + 1;
  }

  // Fused epilogue: partial = sum_d acc * (Xhi+Xlo); division by t in k_sjsum.
  const int b = c0 >> 8;
  const int re = (lane >> 4) * 4, ce = lane & 15;
  float s[8][4];
#pragma unroll
  for (int m = 0; m < 8; ++m)
#pragma unroll
    for (int r = 0; r < 4; ++r) s[m][r] = 0.f;
#pragma unroll
  for (int n = 0; n < 4; ++n) {
    const size_t xrow = (size_t)(c0 + wc * 64 + n * 16 + ce) * Nq;
#pragma unroll
    for (int m = 0; m < 8; ++m) {
      const size_t ib = xrow + i0 + wm * 128 + m * 16 + re;
      ushort4 xh = *(const ushort4*)&Xhi[ib];
      ushort4 xl = *(const ushort4*)&Xlo[ib];
      s[m][0] += acc[m][n][0] * (bf2f(xh.x) + bf2f(xl.x));
      s[m][1] += acc[m][n][1] * (bf2f(xh.y) + bf2f(xl.y));
      s[m][2] += acc[m][n][2] * (bf2f(xh.z) + bf2f(xl.z));
      s[m][3] += acc[m][n][3] * (bf2f(xh.w) + bf2f(xl.w));
    }
  }
#pragma unroll
  for (int o = 1; o < 16; o <<= 1) {
#pragma unroll
    for (int m = 0; m < 8; ++m)
#pragma unroll
      for (int r = 0; r < 4; ++r) s[m][r] += __shfl_xor(s[m][r], o, 64);
  }
  // Coalesced sjp stores: wave-local LDS repack (ds_write -> ds_read same wave,
  // no barrier needed), then two contiguous 256B stores per wave.
  if (ce == 0) {
#pragma unroll
    for (int m = 0; m < 8; ++m)
#pragma unroll
      for (int r = 0; r < 4; ++r)
        swb[wave][m * 16 + re + r] = s[m][r];
  }
  {
    const int slice = (ct & 1) * 8 + ks * 2 + wc;
    float* sp = sjp + ((size_t)slice * Bq + b) * Nq + i0 + wm * 128;
    sp[lane] = swb[wave][lane];
    sp[64 + lane] = swb[wave][64 + lane];
  }
}

// ---- sjv[b,i] = sb[b,i] + (sum of 16 partial slices) / t[b,i] ----
__global__ void k_sjsum(const float* __restrict__ sbA, const float* __restrict__ tA,
                        const float* __restrict__ sjp, float* __restrict__ sjvA) {
  int idx = blockIdx.x * 256 + threadIdx.x;
  float s = 0.f;
#pragma unroll
  for (int sl = 0; sl < 16; ++sl) s += sjp[(size_t)sl * Bq * Nq + idx];
  sjvA[idx] = sbA[idx] + s / tA[idx];
}

// ---- out[b,i,:] = softmax_j( mask(bm, lrelu(si[b,i] + sjv[b,j])) ) ----
__global__ void k_softmax(const unsigned* __restrict__ bm, const float* __restrict__ siA,
                          const float* __restrict__ sjvA, float* __restrict__ out) {
  const int b = blockIdx.y, i = blockIdx.x, tid = threadIdx.x;
  const float siv = siA[(size_t)b * Nq + i];
  const unsigned* brow = bm + (size_t)i * 64;
  const float* sjb = sjvA + (size_t)b * Nq;
  const int bit = tid & 31;
  float sc[8];
  float mx = -3.0e38f;
#pragma unroll
  for (int s = 0; s < 8; ++s) {
    int j = s * 256 + tid;
    float v = siv + sjb[j];
    v = v > 0.f ? v : 0.2f * v;
    unsigned wv = brow[j >> 5];
    v = ((wv >> bit) & 1u) ? v : -9.0e15f;
    sc[s] = v;
    mx = fmaxf(mx, v);
  }
#pragma unroll
  for (int o = 32; o >= 1; o >>= 1) mx = fmaxf(mx, __shfl_xor(mx, o, 64));
  __shared__ float redm[4], reds[4];
  const int wave = tid >> 6, lane = tid & 63;
  if (lane == 0) redm[wave] = mx;
  __syncthreads();
  mx = fmaxf(fmaxf(redm[0], redm[1]), fmaxf(redm[2], redm[3]));
  float sum = 0.f, ex[8];
#pragma unroll
  for (int s = 0; s < 8; ++s) { ex[s] = expf(sc[s] - mx); sum += ex[s]; }
#pragma unroll
  for (int o = 32; o >= 1; o >>= 1) sum += __shfl_xor(sum, o, 64);
  if (lane == 0) reds[wave] = sum;
  __syncthreads();
  sum = reds[0] + reds[1] + reds[2] + reds[3];
  float inv = 1.f / sum;
  float* orow = out + ((size_t)b * Nq + i) * Nq;
#pragma unroll
  for (int s = 0; s < 8; ++s) orow[s * 256 + tid] = ex[s] * inv;
}

extern "C" void kernel_launch(void* const* d_in, const int* in_sizes, int n_in,
                              void* d_out, int out_size, void* d_ws, size_t ws_size,
                              hipStream_t stream) {
  const float* x = (const float*)d_in[0];
  const int* adj = (const int*)d_in[1];
  const float* W = (const float*)d_in[2];
  const float* a = (const float*)d_in[3];
  float* out = (float*)d_out;

  char* ws = (char*)d_ws;
  size_t off = 0;
  auto alloc = [&](size_t bytes) -> void* {
    void* p = ws + off;
    off += (bytes + 255) & ~(size_t)255;
    return p;
  };
  float* w123 = (float*)alloc(3 * DINq * sizeof(float));
  float* WT = (float*)alloc((size_t)DINq * DINq * sizeof(float));
  float* tA = (float*)alloc((size_t)Bq * Nq * sizeof(float));
  float* siA = (float*)alloc((size_t)Bq * Nq * sizeof(float));
  float* sbA = (float*)alloc((size_t)Bq * Nq * sizeof(float));
  float* sjvA = (float*)alloc((size_t)Bq * Nq * sizeof(float));
  float* sjp = (float*)alloc((size_t)16 * Bq * Nq * sizeof(float));
  unsigned short* Xhi = (unsigned short*)alloc((size_t)Nq * Nq * 2);
  unsigned short* Xlo = (unsigned short*)alloc((size_t)Nq * Nq * 2);
  unsigned* bm = (unsigned*)alloc((size_t)Nq * 64 * sizeof(unsigned));

  k_prep<<<dim3(1), dim3(1024), 0, stream>>>(W, a, w123);
  k_transposeW<<<dim3(DINq), dim3(DINq), 0, stream>>>(W, WT);
  k_hX<<<dim3(Nq / 32, Bq), dim3(256), 0, stream>>>(x, WT, w123, Xhi, Xlo, tA, siA, sbA);
  k_mask<<<dim3(Nq * 64 / 256), dim3(256), 0, stream>>>(adj, bm);
  k_gemm<<<dim3(512), dim3(256), 0, stream>>>(bm, Xhi, Xlo, sjp);
  k_sjsum<<<dim3(Bq * Nq / 256), dim3(256), 0, stream>>>(sbA, tA, sjp, sjvA);
  k_softmax<<<dim3(Nq, Bq), dim3(256), 0, stream>>>(bm, siA, sjvA, out);
}

// Round 17
// 127.752 us; speedup vs baseline: 1.3088x; 1.0148x over previous
//
#include <hip/hip_runtime.h>
#include <hip/hip_bf16.h>
#include <math.h>

#define Bq   8
#define DINq 256
#define Nq   2048

typedef __attribute__((ext_vector_type(8))) short bf16x8v;
typedef __attribute__((ext_vector_type(4))) float f32x4v;

__device__ __forceinline__ unsigned short f2bf(float f) {
  union { float f; unsigned u; } v; v.f = f;
  unsigned r = v.u + 0x7fffu + ((v.u >> 16) & 1u);
  return (unsigned short)(r >> 16);
}
__device__ __forceinline__ float bf2f(unsigned short h) {
  union { unsigned u; float f; } v; v.u = ((unsigned)h) << 16;
  return v.f;
}

__device__ __forceinline__ void gld_lds16(const void* g, void* l) {
  __builtin_amdgcn_global_load_lds(
      (const __attribute__((address_space(1))) unsigned int*)g,
      (__attribute__((address_space(3))) unsigned int*)l, 16, 0, 0);
}

// 8 mask bits -> 8 bf16 (1.0/0.0) packed as bf16x8v, element e = bit e.
__device__ __forceinline__ bf16x8v expand_mask(unsigned m8) {
  union { unsigned u[4]; bf16x8v v; } r;
  unsigned lo4 = ((m8 & 0xFu) * 0x204081u) & 0x01010101u;
  unsigned hi4 = (((m8 >> 4) & 0xFu) * 0x204081u) & 0x01010101u;
  r.u[0] = ((lo4 & 0xFFu) | ((lo4 & 0xFF00u) << 8)) * 0x3F80u;
  r.u[1] = (((lo4 >> 16) & 0xFFu) | ((lo4 >> 24) << 16)) * 0x3F80u;
  r.u[2] = ((hi4 & 0xFFu) | ((hi4 & 0xFF00u) << 8)) * 0x3F80u;
  r.u[3] = (((hi4 >> 16) & 0xFFu) | ((hi4 >> 24) << 16)) * 0x3F80u;
  return r.v;
}

// ---- fused: blocks 0..63 transpose W (4 rows each); block 64 computes w123 ----
__global__ void k_wprep(const float* __restrict__ W, const float* __restrict__ a,
                        float* __restrict__ WT, float* __restrict__ w123) {
  __shared__ float red[3][4][256];
  if (blockIdx.x < 64) {
    const int d = blockIdx.x * 4 + (threadIdx.x >> 8);
    const int k = threadIdx.x & 255;
    WT[(size_t)k * DINq + d] = W[(size_t)d * DINq + k];
    return;
  }
  const int k = threadIdx.x & 255, dq = threadIdx.x >> 8;
  float s1 = 0.f, s2 = 0.f, s3 = 0.f;
  for (int d = dq * 64; d < dq * 64 + 64; ++d) {
    float w = W[d * DINq + k];
    s1 += w * a[d];
    s2 += w * a[DINq + d];
    s3 += w * a[2 * DINq + d];
  }
  red[0][dq][k] = s1; red[1][dq][k] = s2; red[2][dq][k] = s3;
  __syncthreads();
  if (threadIdx.x < 256) {
    w123[k]            = red[0][0][k] + red[0][1][k] + red[0][2][k] + red[0][3][k];
    w123[DINq + k]     = red[1][0][k] + red[1][1][k] + red[1][2][k] + red[1][3][k];
    w123[2 * DINq + k] = red[2][0][k] + red[2][1][k] + red[2][2][k] + red[2][3][k];
  }
}

// ---- hX v4 (R13/R16, frozen): 4i x 8d register tile, full d=256/pass ----
__global__ __launch_bounds__(256, 2) void k_hX(const float* __restrict__ x,
                     const float* __restrict__ WT, const float* __restrict__ w123,
                     unsigned short* __restrict__ Xhi, unsigned short* __restrict__ Xlo,
                     float* __restrict__ tA, float* __restrict__ siA,
                     float* __restrict__ sbA) {
  __shared__ float xs[64][32];    // 8 KB   (k x i)
  __shared__ float ws[64][256];   // 64 KB  (k x d)
  __shared__ float wls[768];      // 3 KB
  __shared__ float Tt[32];
  const int tid = threadIdx.x;
  const int iq = tid & 7;         // 8 groups x 4 i = 32 i
  const int dg = tid >> 3;        // 32 groups x 8 d = 256 d
  const int i0 = blockIdx.x * 32;
  const int b = blockIdx.y;
  const int lane = tid & 63;
  const bool w0 = (tid < 64);
  const int ti = lane & 31;
  const int khalf = (lane >> 5) * 32;

  for (int n = tid; n < 768; n += 256) wls[n] = w123[n];

  float acc[4][8];
#pragma unroll
  for (int e = 0; e < 4; ++e)
#pragma unroll
    for (int cc = 0; cc < 8; ++cc) acc[e][cc] = 0.f;
  float p1 = 0.f, p2 = 0.f, p3 = 0.f;

  for (int kc = 0; kc < 4; ++kc) {
    __syncthreads();
#pragma unroll
    for (int l = 0; l < 2; ++l) {
      int c = l * 256 + tid;
      int r = c >> 3, ch = c & 7;
      gld_lds16(&x[((size_t)b * DINq + kc * 64 + r) * Nq + i0 + ch * 4], &xs[r][ch * 4]);
    }
#pragma unroll
    for (int l = 0; l < 16; ++l) {
      int c = l * 256 + tid;
      int r = c >> 6, ch = c & 63;
      gld_lds16(&WT[(size_t)(kc * 64 + r) * DINq + ch * 4], &ws[r][ch * 4]);
    }
    asm volatile("s_waitcnt vmcnt(0)" ::: "memory");
    __syncthreads();
#pragma unroll 4
    for (int kk = 0; kk < 64; ++kk) {
      f32x4v xv = *(const f32x4v*)&xs[kk][iq * 4];
      f32x4v wv0 = *(const f32x4v*)&ws[kk][dg * 8];
      f32x4v wv1 = *(const f32x4v*)&ws[kk][dg * 8 + 4];
#pragma unroll
      for (int e = 0; e < 4; ++e) {
#pragma unroll
        for (int cc = 0; cc < 4; ++cc) {
          acc[e][cc]     += xv[e] * wv0[cc];
          acc[e][cc + 4] += xv[e] * wv1[cc];
        }
      }
    }
    if (w0) {
#pragma unroll 4
      for (int k2 = 0; k2 < 32; ++k2) {
        int kk = khalf + k2;
        float xv = xs[kk][ti];
        p1 += xv * wls[kc * 64 + kk];
        p2 += xv * wls[256 + kc * 64 + kk];
        p3 += xv * wls[512 + kc * 64 + kk];
      }
    }
  }

  if (w0) {
    p1 += __shfl_xor(p1, 32, 64);
    p2 += __shfl_xor(p2, 32, 64);
    p3 += __shfl_xor(p3, 32, 64);
    if (lane < 32) {
      Tt[lane] = p3;
      tA[(size_t)b * Nq + i0 + lane] = p3;
      siA[(size_t)b * Nq + i0 + lane] = p1;
      sbA[(size_t)b * Nq + i0 + lane] = p2;
    }
  }
  __syncthreads();

  float tv[4];
#pragma unroll
  for (int e = 0; e < 4; ++e) tv[e] = Tt[iq * 4 + e];

#pragma unroll
  for (int cc = 0; cc < 8; ++cc) {
    const int d = dg * 8 + cc;
    unsigned short hv[4], lv[4];
#pragma unroll
    for (int e = 0; e < 4; ++e) {
      float Xv = tv[e] * acc[e][cc];
      unsigned short hs = f2bf(Xv);
      hv[e] = hs;
      lv[e] = f2bf(Xv - bf2f(hs));
    }
    size_t off = ((size_t)b * DINq + d) * Nq + i0 + iq * 4;
    *(ushort4*)&Xhi[off] = make_ushort4(hv[0], hv[1], hv[2], hv[3]);
    *(ushort4*)&Xlo[off] = make_ushort4(lv[0], lv[1], lv[2], lv[3]);
  }
}

// ---- bm[i][w] = bitmask of (adj[i][j]!=0), 32 j per word ----
__global__ void k_mask(const int* __restrict__ adj, unsigned* __restrict__ bm) {
  int wg = blockIdx.x * 256 + threadIdx.x;
  int i = wg >> 6, w = wg & 63, j0 = w * 32;
  const int4* ap = (const int4*)&adj[(size_t)i * Nq + j0];
  unsigned bits = 0;
#pragma unroll
  for (int q = 0; q < 8; ++q) {
    int4 a = ap[q];
    if (a.x) bits |= 1u << (q * 4);
    if (a.y) bits |= 1u << (q * 4 + 1);
    if (a.z) bits |= 1u << (q * 4 + 2);
    if (a.w) bits |= 1u << (q * 4 + 3);
  }
  bm[wg] = bits;
}

// ---- GEMM (R16, frozen): R9 structure + coalesced sjp epilogue stores ----
__global__ __launch_bounds__(256, 2) void k_gemm(const unsigned* __restrict__ bm,
                                                 const unsigned short* __restrict__ Xhi,
                                                 const unsigned short* __restrict__ Xlo,
                                                 float* __restrict__ sjp) {
  __shared__ __align__(16) unsigned short Bs[3][2][128 * 32];  // 48 KB
  __shared__ unsigned bmlds[256 * 16];                         // 16 KB
  __shared__ float swb[4][128];                                // 2 KB
  const int tid = threadIdx.x;
  const int lane = tid & 63;
  const int wave = tid >> 6;
  const int wm = wave >> 1, wc = wave & 1;
  const int wg = blockIdx.x;
  const int xcd = wg & 7;
  const int sub = wg >> 3;            // [0,64)
  const int ct = xcd * 2 + (sub & 1);
  const int mt = (sub >> 1) & 7;
  const int ks = sub >> 4;            // [0,4)
  const int i0 = mt * 256, c0 = ct * 128, kbase = ks * 512;
  const int r15 = lane & 15, kg = lane >> 4;
  const int kb = 16 * (kg ^ ((r15 >> 1) & 3));

  {
    const int kw0 = kbase >> 5;
#pragma unroll
    for (int n = 0; n < 4; ++n) {
      int idx4 = n * 256 + tid;
      int r = idx4 >> 2, w4 = (idx4 & 3) * 4;
      uint4 v = *(const uint4*)&bm[(size_t)(i0 + r) * 64 + kw0 + w4];
      bmlds[r * 16 + ((w4 + 0) ^ (r & 15))] = v.x;
      bmlds[r * 16 + ((w4 + 1) ^ (r & 15))] = v.y;
      bmlds[r * 16 + ((w4 + 2) ^ (r & 15))] = v.z;
      bmlds[r * 16 + ((w4 + 3) ^ (r & 15))] = v.w;
    }
  }
  __syncthreads();

  f32x4v acc[8][4];
#pragma unroll
  for (int m = 0; m < 8; ++m)
#pragma unroll
    for (int n = 0; n < 4; ++n) acc[m][n] = (f32x4v)0.f;

  auto STAGE = [&](int buf, int t) {
    const int k0 = kbase + t * 32;
#pragma unroll
    for (int l = 0; l < 2; ++l) {
      const int pc = l * 256 + tid;
      const int row = pc >> 2, q = pc & 3;
      const int kc = 8 * (q ^ ((row >> 1) & 3));
      gld_lds16(&Xhi[(size_t)(c0 + row) * Nq + k0 + kc], &Bs[buf][0][pc * 8]);
      gld_lds16(&Xlo[(size_t)(c0 + row) * Nq + k0 + kc], &Bs[buf][1][pc * 8]);
    }
  };

  constexpr int NT = 16;  // 512 / 32
  STAGE(0, 0);
  STAGE(1, 1);
  int cb = 0, sb2 = 2;
  for (int t = 0; t < NT; ++t) {
    if (t + 1 < NT) {
      asm volatile("s_waitcnt vmcnt(4)" ::: "memory");
    } else {
      asm volatile("s_waitcnt vmcnt(0)" ::: "memory");
    }
    __builtin_amdgcn_sched_barrier(0);
    __builtin_amdgcn_s_barrier();
    __builtin_amdgcn_sched_barrier(0);
    if (t + 2 < NT) STAGE(sb2, t + 2);

    const char* Bh = (const char*)&Bs[cb][0][0];
    const char* Bl = (const char*)&Bs[cb][1][0];
    bf16x8v bfh[4], bfl[4];
#pragma unroll
    for (int n = 0; n < 4; ++n) {
      bfh[n] = *(const bf16x8v*)(Bh + (wc * 64 + n * 16 + r15) * 64 + kb);
      bfl[n] = *(const bf16x8v*)(Bl + (wc * 64 + n * 16 + r15) * 64 + kb);
    }
    const int jb = kbase + t * 32 + kg * 8;
#pragma unroll
    for (int m = 0; m < 8; ++m) {
      const int arow = wm * 128 + m * 16 + r15;
      unsigned wv = bmlds[arow * 16 + (t ^ (arow & 15))];
      unsigned m8 = (wv >> (kg * 8)) & 0xFFu;
      unsigned d = (unsigned)(i0 + arow - jb);
      if (d < 8u) m8 &= ~(1u << d);
      bf16x8v af = expand_mask(m8);
      __builtin_amdgcn_s_setprio(1);
#pragma unroll
      for (int n = 0; n < 4; ++n) {
        acc[m][n] = __builtin_amdgcn_mfma_f32_16x16x32_bf16(af, bfh[n], acc[m][n], 0, 0, 0);
        acc[m][n] = __builtin_amdgcn_mfma_f32_16x16x32_bf16(af, bfl[n], acc[m][n], 0, 0, 0);
      }
      __builtin_amdgcn_s_setprio(0);
    }
    cb = (cb == 2) ? 0 : cb + 1;
    sb2 = (sb2 == 2) ? 0 : sb2 + 1;
  }

  // Fused epilogue: partial = sum_d acc * (Xhi+Xlo); division by t in k_sjsum.
  const int b = c0 >> 8;
  const int re = (lane >> 4) * 4, ce = lane & 15;
  float s[8][4];
#pragma unroll
  for (int m = 0; m < 8; ++m)
#pragma unroll
    for (int r = 0; r < 4; ++r) s[m][r] = 0.f;
#pragma unroll
  for (int n = 0; n < 4; ++n) {
    const size_t xrow = (size_t)(c0 + wc * 64 + n * 16 + ce) * Nq;
#pragma unroll
    for (int m = 0; m < 8; ++m) {
      const size_t ib = xrow + i0 + wm * 128 + m * 16 + re;
      ushort4 xh = *(const ushort4*)&Xhi[ib];
      ushort4 xl = *(const ushort4*)&Xlo[ib];
      s[m][0] += acc[m][n][0] * (bf2f(xh.x) + bf2f(xl.x));
      s[m][1] += acc[m][n][1] * (bf2f(xh.y) + bf2f(xl.y));
      s[m][2] += acc[m][n][2] * (bf2f(xh.z) + bf2f(xl.z));
      s[m][3] += acc[m][n][3] * (bf2f(xh.w) + bf2f(xl.w));
    }
  }
#pragma unroll
  for (int o = 1; o < 16; o <<= 1) {
#pragma unroll
    for (int m = 0; m < 8; ++m)
#pragma unroll
      for (int r = 0; r < 4; ++r) s[m][r] += __shfl_xor(s[m][r], o, 64);
  }
  // Coalesced sjp stores: wave-local LDS repack, two contiguous 256B stores.
  if (ce == 0) {
#pragma unroll
    for (int m = 0; m < 8; ++m)
#pragma unroll
      for (int r = 0; r < 4; ++r)
        swb[wave][m * 16 + re + r] = s[m][r];
  }
  {
    const int slice = (ct & 1) * 8 + ks * 2 + wc;
    float* sp = sjp + ((size_t)slice * Bq + b) * Nq + i0 + wm * 128;
    sp[lane] = swb[wave][lane];
    sp[64 + lane] = swb[wave][64 + lane];
  }
}

// ---- sjv[b,i] = sb[b,i] + (sum of 16 partial slices) / t[b,i] ----
__global__ void k_sjsum(const float* __restrict__ sbA, const float* __restrict__ tA,
                        const float* __restrict__ sjp, float* __restrict__ sjvA) {
  int idx = blockIdx.x * 256 + threadIdx.x;
  float s = 0.f;
#pragma unroll
  for (int sl = 0; sl < 16; ++sl) s += sjp[(size_t)sl * Bq * Nq + idx];
  sjvA[idx] = sbA[idx] + s / tA[idx];
}

// ---- out[b,i,:] = softmax_j( mask(bm, lrelu(si[b,i] + sjv[b,j])) ) ----
__global__ void k_softmax(const unsigned* __restrict__ bm, const float* __restrict__ siA,
                          const float* __restrict__ sjvA, float* __restrict__ out) {
  const int b = blockIdx.y, i = blockIdx.x, tid = threadIdx.x;
  const float siv = siA[(size_t)b * Nq + i];
  const unsigned* brow = bm + (size_t)i * 64;
  const float* sjb = sjvA + (size_t)b * Nq;
  const int bit = tid & 31;
  float sc[8];
  float mx = -3.0e38f;
#pragma unroll
  for (int s = 0; s < 8; ++s) {
    int j = s * 256 + tid;
    float v = siv + sjb[j];
    v = v > 0.f ? v : 0.2f * v;
    unsigned wv = brow[j >> 5];
    v = ((wv >> bit) & 1u) ? v : -9.0e15f;
    sc[s] = v;
    mx = fmaxf(mx, v);
  }
#pragma unroll
  for (int o = 32; o >= 1; o >>= 1) mx = fmaxf(mx, __shfl_xor(mx, o, 64));
  __shared__ float redm[4], reds[4];
  const int wave = tid >> 6, lane = tid & 63;
  if (lane == 0) redm[wave] = mx;
  __syncthreads();
  mx = fmaxf(fmaxf(redm[0], redm[1]), fmaxf(redm[2], redm[3]));
  float sum = 0.f, ex[8];
#pragma unroll
  for (int s = 0; s < 8; ++s) { ex[s] = expf(sc[s] - mx); sum += ex[s]; }
#pragma unroll
  for (int o = 32; o >= 1; o >>= 1) sum += __shfl_xor(sum, o, 64);
  if (lane == 0) reds[wave] = sum;
  __syncthreads();
  sum = reds[0] + reds[1] + reds[2] + reds[3];
  float inv = 1.f / sum;
  float* orow = out + ((size_t)b * Nq + i) * Nq;
#pragma unroll
  for (int s = 0; s < 8; ++s) orow[s * 256 + tid] = ex[s] * inv;
}

extern "C" void kernel_launch(void* const* d_in, const int* in_sizes, int n_in,
                              void* d_out, int out_size, void* d_ws, size_t ws_size,
                              hipStream_t stream) {
  const float* x = (const float*)d_in[0];
  const int* adj = (const int*)d_in[1];
  const float* W = (const float*)d_in[2];
  const float* a = (const float*)d_in[3];
  float* out = (float*)d_out;

  char* ws = (char*)d_ws;
  size_t off = 0;
  auto alloc = [&](size_t bytes) -> void* {
    void* p = ws + off;
    off += (bytes + 255) & ~(size_t)255;
    return p;
  };
  float* w123 = (float*)alloc(3 * DINq * sizeof(float));
  float* WT = (float*)alloc((size_t)DINq * DINq * sizeof(float));
  float* tA = (float*)alloc((size_t)Bq * Nq * sizeof(float));
  float* siA = (float*)alloc((size_t)Bq * Nq * sizeof(float));
  float* sbA = (float*)alloc((size_t)Bq * Nq * sizeof(float));
  float* sjvA = (float*)alloc((size_t)Bq * Nq * sizeof(float));
  float* sjp = (float*)alloc((size_t)16 * Bq * Nq * sizeof(float));
  unsigned short* Xhi = (unsigned short*)alloc((size_t)Nq * Nq * 2);
  unsigned short* Xlo = (unsigned short*)alloc((size_t)Nq * Nq * 2);
  unsigned* bm = (unsigned*)alloc((size_t)Nq * 64 * sizeof(unsigned));

  k_wprep<<<dim3(65), dim3(1024), 0, stream>>>(W, a, WT, w123);
  k_hX<<<dim3(Nq / 32, Bq), dim3(256), 0, stream>>>(x, WT, w123, Xhi, Xlo, tA, siA, sbA);
  k_mask<<<dim3(Nq * 64 / 256), dim3(256), 0, stream>>>(adj, bm);
  k_gemm<<<dim3(512), dim3(256), 0, stream>>>(bm, Xhi, Xlo, sjp);
  k_sjsum<<<dim3(Bq * Nq / 256), dim3(256), 0, stream>>>(sbA, tA, sjp, sjvA);
  k_softmax<<<dim3(Nq, Bq), dim3(256), 0, stream>>>(bm, siA, sjvA, out);
}